// Round 8
// baseline (267.514 us; speedup 1.0000x reference)
//
#include <hip/hip_runtime.h>
#include <hip/hip_fp16.h>

// GCN layer: h = x @ W_conv; conv = D^-1/2 (A+I) D^-1/2 h + b_conv; out = conv @ W_lin + b_lin
// N=50000, E=800000, in_c=256, hid=128.
// h, conv in bf16 row-major. CSR stored as packed u32 records (src u16 | fp16 weight).
//
// R7 ledger: kernel-internal changes move the total <=3us; ~80us of the 229 is
// inter-dispatch dead time (8 serial dispatches). This round: 8 -> 6 dispatches.
// scan_blocks + finalize2 + bucket merge into ONE csr_kernel: each class-filtered
// block re-derives its class's row_ptr locally (redundant reduce of L2-resident deg
// + LDS scan of the class's 6250 degs) — no cross-block dependency, no global
// barrier. dinv array deleted; bucket/gather compute rsqrtf(deg+1) inline.
//
// Pipeline (6 dispatches, stream-serial):
//   memset(deg) -> prep(W transposes + deg/rank) -> csr(row_ptr + fill)
//   -> GEMM1 (reg-prefetch) -> gather (MLP x2) -> GEMM2 (reg-prefetch)

#define N_NODES 50000
#define N_EDGES 800000
#define IN_C 256
#define HID 128
#define GEMM_MBLK ((N_NODES + 63) / 64)       // 782
#define PREP_BLOCKS 1024
#define CSR_BLOCKS 2048                       // 8 classes x 256 chunk-blocks
#define CSIZE (N_NODES / 8)                   // 6250 nodes per class
#define LDK 72                                 // 64 + 8 pad (bf16 elems)

// workspace layout (bytes)
#define OFF_H    0UL          // [N][128] bf16 = 12,800,000
#define OFF_CONV 12800000UL   // [N][128] bf16 = 12,800,000
#define OFF_DEG  25600000UL   // 50000 i32
#define OFF_RP   25800000UL   // 50001 i32 (pad to 64)
#define OFF_DINV 26000064UL   // (unused now)
#define OFF_RANK 26200064UL   // 800000 u16 = 1,600,000
#define OFF_REC  27800064UL   // 800000 u32 = 3,200,000
#define OFF_BSUM 31000064UL   // (unused now)
#define OFF_WT1  31001088UL   // 128*256 bf16 (W_conv^T)
#define OFF_WT2  31066624UL   // 256*128 bf16 (W_lin^T)

typedef __attribute__((ext_vector_type(8))) short bf16x8;
typedef __attribute__((ext_vector_type(4))) float f32x4;

__device__ __forceinline__ ushort f2bf(float x) {
    unsigned u = __float_as_uint(x);
    u += 0x7fffu + ((u >> 16) & 1u);       // round-to-nearest-even
    return (ushort)(u >> 16);
}

// fused: transpose both weight matrices to bf16 [N][K] + deg count / rank capture.
// deg must be zeroed before this kernel (memset on the same stream).
__global__ __launch_bounds__(256) void prep_kernel(
    const float* __restrict__ Wc, const float* __restrict__ Wl,
    ushort* __restrict__ wtc, ushort* __restrict__ wtl,
    const int* __restrict__ dst, ushort* __restrict__ rank, int* __restrict__ deg)
{
    int i = blockIdx.x * 256 + threadIdx.x;
    if (i < HID * IN_C) {                            // W_conv [256][128] -> [128][256]
        int n = i / IN_C, k = i % IN_C;
        wtc[i] = f2bf(Wc[k * HID + n]);
    } else if (i < 2 * HID * IN_C) {                 // W_lin [128][256] -> [256][128]
        int j = i - HID * IN_C;
        int n = j / HID, k = j % HID;
        wtl[j] = f2bf(Wl[k * IN_C + n]);
    }
    for (int e = i; e < N_EDGES; e += PREP_BLOCKS * 256)
        rank[e] = (ushort)atomicAdd(&deg[dst[e]], 1);
}

// Merged scan+finalize+bucket. 2048 blocks = 8 classes (XCD-aligned) x 256 edge
// chunks. Each block: (1) base = reduce(deg[0..lo)) — redundant, L2-resident;
// (2) exclusive-scan its class's 6250 degs into LDS rp[] (+base); (3) class-c
// blk-0 publishes global row_ptr for the gather; (4) fill rec[] for its edge
// chunk using LDS rp. No cross-block dependency anywhere.
__global__ __launch_bounds__(256) void csr_kernel(
    const int* __restrict__ src, const int* __restrict__ dst,
    const ushort* __restrict__ rank, const int* __restrict__ deg,
    int* __restrict__ row_ptr, unsigned* __restrict__ rec)
{
    __shared__ int rp[CSIZE];          // 25000 B
    __shared__ int tmp[256];
    int tid = threadIdx.x;
    int cls = blockIdx.x & 7;
    int blk = blockIdx.x >> 3;                 // 0..255
    int lo = cls * CSIZE;

    // phase 1: base = sum(deg[0..lo))
    int sum = 0;
    for (int i = tid; i < lo; i += 256) sum += deg[i];
    tmp[tid] = sum;
    __syncthreads();
    #pragma unroll
    for (int off = 128; off > 0; off >>= 1) {
        if (tid < off) tmp[tid] += tmp[tid + off];
        __syncthreads();
    }
    int base = tmp[0];
    __syncthreads();                           // tmp reused below

    // phase 2: exclusive scan of deg[lo..lo+6250) into rp (+base).
    // thread t (t<250) owns 25 consecutive elements.
    int vals[25];
    int tsum = 0;
    if (tid < 250) {
        #pragma unroll
        for (int j = 0; j < 25; ++j) {
            vals[j] = deg[lo + tid * 25 + j];
            tsum += vals[j];
        }
    }
    tmp[tid] = tsum;
    __syncthreads();
    #pragma unroll
    for (int off = 1; off < 256; off <<= 1) {
        int t = (tid >= off) ? tmp[tid - off] : 0;
        __syncthreads();
        tmp[tid] += t;
        __syncthreads();
    }
    int run = base + tmp[tid] - tsum;          // exclusive prefix for this thread
    if (tid < 250) {
        #pragma unroll
        for (int j = 0; j < 25; ++j) {
            rp[tid * 25 + j] = run;
            run += vals[j];
        }
    }
    __syncthreads();

    // phase 3: class writer (blk 0) publishes global row_ptr for the gather
    if (blk == 0) {
        for (int i = tid; i < CSIZE; i += 256)
            row_ptr[lo + i] = rp[i];
        if (cls == 7 && tid == 0) row_ptr[N_NODES] = N_EDGES;
    }

    // phase 4: edge fill from LDS rp. rec = src u16 | fp16(rsqrt(deg[src]+1)) << 16
    const int CHUNK = N_EDGES / 256;           // 3125 (exact)
    int e0 = blk * CHUNK;
    int e1 = e0 + CHUNK;
    for (int i = e0 + tid; i < e1; i += 256) {
        int d = dst[i];
        unsigned rel = (unsigned)(d - lo);
        if (rel < (unsigned)CSIZE) {
            int s = src[i];
            float dis = rsqrtf((float)(deg[s] + 1));
            unsigned r = (unsigned)(ushort)s |
                         ((unsigned)__half_as_ushort(__float2half_rn(dis)) << 16);
            rec[rp[rel] + rank[i]] = r;
        }
    }
}

// ---------------- register-prefetch MFMA GEMM ----------------
// C[M,N] = A[M,KT] @ B[KT,N] (+bias). Tile 64x128, BK=64, KT compile-time.
// Iter k+1's global loads are issued BEFORE iter k's barriers/MFMA.
template <int KT, bool A_IS_BF16, bool BF16OUT>
__global__ __launch_bounds__(256) void mfma_gemm_kernel(
    const void* __restrict__ Av, const ushort* __restrict__ Bt,
    const float* __restrict__ bias, void* __restrict__ Cv,
    int M, int N)
{
    constexpr int NIT = KT / 64;
    __shared__ __align__(16) ushort As[64 * LDK];
    __shared__ __align__(16) ushort Bs[128 * LDK];
    int tid = threadIdx.x;
    int wave = tid >> 6, lane = tid & 63;
    int quad = lane >> 4, l16 = lane & 15;
    int wm0 = (wave >> 1) * 32, wn0 = (wave & 1) * 64;
    int bm = blockIdx.x * 64, bn = blockIdx.y * 128;

    int arow = tid >> 2, acol = (tid & 3) * 16;   // A: 64 rows x 64 k
    int agrow = bm + arow;
    int brow = tid >> 1, bkk = (tid & 1) * 32;    // B: 128 rows x 64 k

    f32x4 acc[2][4] = {};
    float4 a32[2][4];
    bf16x8 a16[2][2];
    bf16x8 breg[2][4];

    auto issue = [&](int it, int s) {
        int k0 = it * 64;
        if (A_IS_BF16) {
            a16[s][0] = bf16x8{};
            a16[s][1] = bf16x8{};
            if (agrow < M) {
                const ushort* ap = (const ushort*)Av + (size_t)agrow * KT + k0 + acol;
                a16[s][0] = *(const bf16x8*)ap;
                a16[s][1] = *(const bf16x8*)(ap + 8);
            }
        } else {
            a32[s][0] = a32[s][1] = a32[s][2] = a32[s][3] = make_float4(0.f, 0.f, 0.f, 0.f);
            if (agrow < M) {
                const float* ap = (const float*)Av + (size_t)agrow * KT + k0 + acol;
                a32[s][0] = *(const float4*)ap;
                a32[s][1] = *(const float4*)(ap + 4);
                a32[s][2] = *(const float4*)(ap + 8);
                a32[s][3] = *(const float4*)(ap + 12);
            }
        }
        const ushort* bp = Bt + (size_t)(bn + brow) * KT + k0 + bkk;
        breg[s][0] = *(const bf16x8*)bp;
        breg[s][1] = *(const bf16x8*)(bp + 8);
        breg[s][2] = *(const bf16x8*)(bp + 16);
        breg[s][3] = *(const bf16x8*)(bp + 24);
    };

    auto stage = [&](int s) {
        if (A_IS_BF16) {
            *(bf16x8*)&As[arow * LDK + acol]     = a16[s][0];
            *(bf16x8*)&As[arow * LDK + acol + 8] = a16[s][1];
        } else {
            ushort t0[8] = {f2bf(a32[s][0].x), f2bf(a32[s][0].y), f2bf(a32[s][0].z), f2bf(a32[s][0].w),
                            f2bf(a32[s][1].x), f2bf(a32[s][1].y), f2bf(a32[s][1].z), f2bf(a32[s][1].w)};
            ushort t1[8] = {f2bf(a32[s][2].x), f2bf(a32[s][2].y), f2bf(a32[s][2].z), f2bf(a32[s][2].w),
                            f2bf(a32[s][3].x), f2bf(a32[s][3].y), f2bf(a32[s][3].z), f2bf(a32[s][3].w)};
            *(bf16x8*)&As[arow * LDK + acol]     = *(bf16x8*)t0;
            *(bf16x8*)&As[arow * LDK + acol + 8] = *(bf16x8*)t1;
        }
        *(bf16x8*)&Bs[brow * LDK + bkk]      = breg[s][0];
        *(bf16x8*)&Bs[brow * LDK + bkk + 8]  = breg[s][1];
        *(bf16x8*)&Bs[brow * LDK + bkk + 16] = breg[s][2];
        *(bf16x8*)&Bs[brow * LDK + bkk + 24] = breg[s][3];
    };

    issue(0, 0);
    #pragma unroll
    for (int it = 0; it < NIT; ++it) {
        int cur = it & 1;
        if (it + 1 < NIT) issue(it + 1, cur ^ 1);
        if (it > 0) __syncthreads();
        stage(cur);
        __syncthreads();
        bf16x8 af[2][2], bfr[4][2];
        #pragma unroll
        for (int im = 0; im < 2; ++im)
            #pragma unroll
            for (int kh = 0; kh < 2; ++kh)
                af[im][kh] = *(bf16x8*)&As[(wm0 + im * 16 + l16) * LDK + kh * 32 + quad * 8];
        #pragma unroll
        for (int in = 0; in < 4; ++in)
            #pragma unroll
            for (int kh = 0; kh < 2; ++kh)
                bfr[in][kh] = *(bf16x8*)&Bs[(wn0 + in * 16 + l16) * LDK + kh * 32 + quad * 8];
        #pragma unroll
        for (int im = 0; im < 2; ++im)
            #pragma unroll
            for (int in = 0; in < 4; ++in) {
                acc[im][in] = __builtin_amdgcn_mfma_f32_16x16x32_bf16(
                    af[im][0], bfr[in][0], acc[im][in], 0, 0, 0);
                acc[im][in] = __builtin_amdgcn_mfma_f32_16x16x32_bf16(
                    af[im][1], bfr[in][1], acc[im][in], 0, 0, 0);
            }
    }
    #pragma unroll
    for (int im = 0; im < 2; ++im) {
        #pragma unroll
        for (int in = 0; in < 4; ++in) {
            int col = bn + wn0 + in * 16 + l16;
            float bval = bias ? bias[col] : 0.f;
            #pragma unroll
            for (int r = 0; r < 4; ++r) {
                int grow = bm + wm0 + im * 16 + quad * 4 + r;
                if (grow < M) {
                    float o = acc[im][in][r] + bval;
                    if (BF16OUT)
                        ((ushort*)Cv)[(size_t)grow * N + col] = f2bf(o);
                    else
                        ((float*)Cv)[(size_t)grow * N + col] = o;
                }
            }
        }
    }
}

// ---------------- gather ----------------
// convb[d][:] = bf16( di*( sum_in w_s*h[s][:] + di*h[d][:] ) + b_conv )
// wave64 per node; two 32-lane halves process alternate edges; unroll 8 per half
// (16 h-row loads in flight per wave). di computed inline from deg (dinv deleted).
__device__ __forceinline__ void acc_edge(float4& acc, unsigned r,
                                         const ushort* __restrict__ hb, int c) {
    unsigned s = r & 0xffffu;
    float w = __half2float(__ushort_as_half((ushort)(r >> 16)));
    uint2 v = *(const uint2*)&hb[(size_t)s * HID + c];
    acc.x += w * __uint_as_float(v.x << 16);
    acc.y += w * __uint_as_float(v.x & 0xffff0000u);
    acc.z += w * __uint_as_float(v.y << 16);
    acc.w += w * __uint_as_float(v.y & 0xffff0000u);
}

__global__ __launch_bounds__(256, 4) void gather_kernel(
    const ushort* __restrict__ hb, const int* __restrict__ row_ptr,
    const unsigned* __restrict__ rec, const int* __restrict__ deg,
    const float* __restrict__ b_conv, ushort* __restrict__ convb, int n)
{
    int wave = threadIdx.x >> 6;
    int lane = threadIdx.x & 63;
    int d = blockIdx.x * 4 + wave;
    if (d >= n) return;
    int half = lane >> 5;
    int l32 = lane & 31;
    int c = l32 << 2;                 // 4 cols per lane

    float4 acc = make_float4(0.f, 0.f, 0.f, 0.f);
    int begin = row_ptr[d], end = row_ptr[d + 1];
    int e = begin + half;             // this half's edges: e, e+2, e+4, ...
    for (; e + 14 < end; e += 16) {   // 8 edges per half per iter
        unsigned r0 = rec[e];
        unsigned r1 = rec[e + 2];
        unsigned r2 = rec[e + 4];
        unsigned r3 = rec[e + 6];
        unsigned r4 = rec[e + 8];
        unsigned r5 = rec[e + 10];
        unsigned r6 = rec[e + 12];
        unsigned r7 = rec[e + 14];
        acc_edge(acc, r0, hb, c);
        acc_edge(acc, r1, hb, c);
        acc_edge(acc, r2, hb, c);
        acc_edge(acc, r3, hb, c);
        acc_edge(acc, r4, hb, c);
        acc_edge(acc, r5, hb, c);
        acc_edge(acc, r6, hb, c);
        acc_edge(acc, r7, hb, c);
    }
    for (; e + 6 < end; e += 8) {
        unsigned r0 = rec[e];
        unsigned r1 = rec[e + 2];
        unsigned r2 = rec[e + 4];
        unsigned r3 = rec[e + 6];
        acc_edge(acc, r0, hb, c);
        acc_edge(acc, r1, hb, c);
        acc_edge(acc, r2, hb, c);
        acc_edge(acc, r3, hb, c);
    }
    for (; e < end; e += 2) {
        unsigned r0 = rec[e];
        acc_edge(acc, r0, hb, c);
    }
    acc.x += __shfl_xor(acc.x, 32);
    acc.y += __shfl_xor(acc.y, 32);
    acc.z += __shfl_xor(acc.z, 32);
    acc.w += __shfl_xor(acc.w, 32);

    if (half == 0) {
        float di = rsqrtf((float)(deg[d] + 1));
        uint2 hv = *(const uint2*)&hb[(size_t)d * HID + c];
        acc.x += di * __uint_as_float(hv.x << 16);
        acc.y += di * __uint_as_float(hv.x & 0xffff0000u);
        acc.z += di * __uint_as_float(hv.y << 16);
        acc.w += di * __uint_as_float(hv.y & 0xffff0000u);
        float4 bb = *(const float4*)&b_conv[c];
        float ox = di * acc.x + bb.x;
        float oy = di * acc.y + bb.y;
        float oz = di * acc.z + bb.z;
        float ow = di * acc.w + bb.w;
        uint2 po;
        po.x = ((unsigned)f2bf(oy) << 16) | (unsigned)f2bf(ox);
        po.y = ((unsigned)f2bf(ow) << 16) | (unsigned)f2bf(oz);
        *(uint2*)&convb[(size_t)d * HID + c] = po;
    }
}

extern "C" void kernel_launch(void* const* d_in, const int* in_sizes, int n_in,
                              void* d_out, int out_size, void* d_ws, size_t ws_size,
                              hipStream_t stream) {
    const float* x      = (const float*)d_in[0];
    const int*   ei     = (const int*)d_in[1];
    const float* W_conv = (const float*)d_in[2];
    const float* b_conv = (const float*)d_in[3];
    const float* W_lin  = (const float*)d_in[4];
    const float* b_lin  = (const float*)d_in[5];
    float* out = (float*)d_out;

    char* ws = (char*)d_ws;
    ushort* hb      = (ushort*)(ws + OFF_H);
    ushort* convb   = (ushort*)(ws + OFF_CONV);
    int*    deg     = (int*)(ws + OFF_DEG);
    int*    row_ptr = (int*)(ws + OFF_RP);
    ushort* rank    = (ushort*)(ws + OFF_RANK);
    unsigned* rec   = (unsigned*)(ws + OFF_REC);
    ushort* wt_conv = (ushort*)(ws + OFF_WT1);
    ushort* wt_lin  = (ushort*)(ws + OFF_WT2);

    const int* src = ei;
    const int* dst = ei + N_EDGES;

    hipMemsetAsync(deg, 0, 200000, stream);

    // K1: W transposes + deg/rank
    prep_kernel<<<PREP_BLOCKS, 256, 0, stream>>>(W_conv, W_lin, wt_conv, wt_lin,
                                                 dst, rank, deg);

    // K2: merged scan+finalize+bucket (per-class local row_ptr derivation)
    csr_kernel<<<CSR_BLOCKS, 256, 0, stream>>>(src, dst, rank, deg, row_ptr, rec);

    // K3: h = bf16(x @ W_conv) — register-prefetch GEMM
    mfma_gemm_kernel<IN_C, false, true><<<dim3(GEMM_MBLK, HID / 128), 256, 0, stream>>>(
        x, wt_conv, nullptr, hb, N_NODES, HID);

    // K4: gather (MLP x2, inline rsqrt)
    gather_kernel<<<(N_NODES + 3) / 4, 256, 0, stream>>>(
        hb, row_ptr, rec, deg, b_conv, convb, N_NODES);

    // K5: out = conv @ W_lin + b_lin — register-prefetch GEMM
    mfma_gemm_kernel<HID, true, false><<<dim3(GEMM_MBLK, IN_C / 128), 256, 0, stream>>>(
        convb, wt_lin, b_lin, out, N_NODES, IN_C);
}

// Round 9
// 236.172 us; speedup vs baseline: 1.1327x; 1.1327x over previous
//
#include <hip/hip_runtime.h>
#include <hip/hip_fp16.h>

// GCN layer: h = x @ W_conv; conv = D^-1/2 (A+I) D^-1/2 h + b_conv; out = conv @ W_lin + b_lin
// N=50000, E=800000, in_c=256, hid=128.
// h, conv in bf16 row-major. CSR stored as packed u32 records (src u16 | fp16 weight).
//
// R8 post-mortem: csr mega-merge = 63.8us (redundant 43k-element reduces x 2048
// blocks). REVERTED to R7 (229.0us best). Merge rule learned: only merge when the
// redundant work << ~10us dispatch gap AND occupancy is untaxed.
// This round: the one merge that satisfies it — scan_blocks+finalize2 -> scanfin
// (196 blocks; each block redundantly computes the 196 chunk-sums itself: 256
// L2-resident loads/thread, ~2-3us, no cross-block dependency).
//
// Pipeline (7 dispatches, stream-serial):
//   memset(deg) -> prep(W transposes + deg/rank) -> scanfin(row_ptr+dinv)
//   -> bucket -> GEMM1 (reg-prefetch) -> gather (MLP x2) -> GEMM2 (reg-prefetch)

#define N_NODES 50000
#define N_EDGES 800000
#define IN_C 256
#define HID 128
#define SCAN_BLOCKS ((N_NODES + 255) / 256)   // 196
#define GEMM_MBLK ((N_NODES + 63) / 64)       // 782
#define PREP_BLOCKS 1024
#define BUCKET_BLOCKS 2048                    // 8 classes x 256 chunk-blocks, 0 LDS
#define LDK 72                                 // 64 + 8 pad (bf16 elems)

// workspace layout (bytes)
#define OFF_H    0UL          // [N][128] bf16 = 12,800,000
#define OFF_CONV 12800000UL   // [N][128] bf16 = 12,800,000
#define OFF_DEG  25600000UL   // 50000 i32
#define OFF_RP   25800000UL   // 50001 i32 (pad to 64)
#define OFF_DINV 26000064UL   // 50000 f32
#define OFF_RANK 26200064UL   // 800000 u16 = 1,600,000
#define OFF_REC  27800064UL   // 800000 u32 = 3,200,000
#define OFF_WT1  31001088UL   // 128*256 bf16 (W_conv^T)
#define OFF_WT2  31066624UL   // 256*128 bf16 (W_lin^T)

typedef __attribute__((ext_vector_type(8))) short bf16x8;
typedef __attribute__((ext_vector_type(4))) float f32x4;

__device__ __forceinline__ ushort f2bf(float x) {
    unsigned u = __float_as_uint(x);
    u += 0x7fffu + ((u >> 16) & 1u);       // round-to-nearest-even
    return (ushort)(u >> 16);
}

// fused: transpose both weight matrices to bf16 [N][K] + deg count / rank capture.
// deg must be zeroed before this kernel (memset on the same stream).
__global__ __launch_bounds__(256) void prep_kernel(
    const float* __restrict__ Wc, const float* __restrict__ Wl,
    ushort* __restrict__ wtc, ushort* __restrict__ wtl,
    const int* __restrict__ dst, ushort* __restrict__ rank, int* __restrict__ deg)
{
    int i = blockIdx.x * 256 + threadIdx.x;
    if (i < HID * IN_C) {                            // W_conv [256][128] -> [128][256]
        int n = i / IN_C, k = i % IN_C;
        wtc[i] = f2bf(Wc[k * HID + n]);
    } else if (i < 2 * HID * IN_C) {                 // W_lin [128][256] -> [256][128]
        int j = i - HID * IN_C;
        int n = j / HID, k = j % HID;
        wtl[j] = f2bf(Wl[k * IN_C + n]);
    }
    for (int e = i; e < N_EDGES; e += PREP_BLOCKS * 256)
        rank[e] = (ushort)atomicAdd(&deg[dst[e]], 1);
}

// merged scan_blocks + finalize2: 196 blocks. Each block redundantly computes all
// 196 chunk-sums (thread t sums deg[t*256..+256), L2-resident), LDS-scans them for
// its own base offset, then exclusive-scans its 256-node window -> row_ptr, dinv.
__global__ __launch_bounds__(256) void scanfin_kernel(
    const int* __restrict__ deg, int* __restrict__ row_ptr,
    float* __restrict__ dinv, int n)
{
    __shared__ int bsum[256];
    __shared__ int bscan[256];
    __shared__ int tmp[256];
    int tid = threadIdx.x;

    // phase 1: chunk sums (redundant per block; deg is L2-resident after prep)
    int s = 0;
    if (tid < SCAN_BLOCKS) {
        const int* p = deg + tid * 256;
        int lim = min(256, n - tid * 256);
        #pragma unroll 8
        for (int j = 0; j < lim; ++j) s += p[j];
    }
    bsum[tid] = s;
    bscan[tid] = s;
    __syncthreads();

    // phase 2: inclusive scan of chunk sums
    #pragma unroll
    for (int off = 1; off < 256; off <<= 1) {
        int t = (tid >= off) ? bscan[tid - off] : 0;
        __syncthreads();
        bscan[tid] += t;
        __syncthreads();
    }
    int base = bscan[blockIdx.x] - bsum[blockIdx.x];   // exclusive prefix of this block

    // phase 3: this block's 256-node window
    int i = blockIdx.x * 256 + tid;
    int v = (i < n) ? deg[i] : 0;
    tmp[tid] = v;
    __syncthreads();
    #pragma unroll
    for (int off = 1; off < 256; off <<= 1) {
        int t = (tid >= off) ? tmp[tid - off] : 0;
        __syncthreads();
        tmp[tid] += t;
        __syncthreads();
    }
    if (i < n) {
        row_ptr[i] = base + tmp[tid] - v;
        dinv[i] = rsqrtf((float)(v + 1));
    }
    if (i == 0) row_ptr[n] = N_EDGES;
}

// CSR fill, atomic-free, XCD-class filtered (blockIdx%8 handles one dst range), 0 LDS.
__global__ __launch_bounds__(256) void bucket_kernel(
    const int* __restrict__ src, const int* __restrict__ dst,
    const ushort* __restrict__ rank, const int* __restrict__ row_ptr,
    const float* __restrict__ dinv, unsigned* __restrict__ rec)
{
    int cls = blockIdx.x & 7;
    int blk = blockIdx.x >> 3;                 // 0..255
    int lo = cls * (N_NODES / 8);              // 6250 per class
    int hi = lo + (N_NODES / 8);
    const int CHUNK = (N_EDGES + 255) / 256;   // 3125
    int e0 = blk * CHUNK;
    int e1 = min(e0 + CHUNK, N_EDGES);
    for (int i = e0 + threadIdx.x; i < e1; i += 256) {
        int d = dst[i];
        if (d >= lo && d < hi) {
            int s = src[i];
            unsigned r = (unsigned)(ushort)s |
                         ((unsigned)__half_as_ushort(__float2half_rn(dinv[s])) << 16);
            rec[row_ptr[d] + rank[i]] = r;
        }
    }
}

// ---------------- register-prefetch MFMA GEMM ----------------
// C[M,N] = A[M,KT] @ B[KT,N] (+bias). Tile 64x128, BK=64, KT compile-time.
// Iter k+1's global loads are issued BEFORE iter k's barriers/MFMA.
template <int KT, bool A_IS_BF16, bool BF16OUT>
__global__ __launch_bounds__(256) void mfma_gemm_kernel(
    const void* __restrict__ Av, const ushort* __restrict__ Bt,
    const float* __restrict__ bias, void* __restrict__ Cv,
    int M, int N)
{
    constexpr int NIT = KT / 64;
    __shared__ __align__(16) ushort As[64 * LDK];
    __shared__ __align__(16) ushort Bs[128 * LDK];
    int tid = threadIdx.x;
    int wave = tid >> 6, lane = tid & 63;
    int quad = lane >> 4, l16 = lane & 15;
    int wm0 = (wave >> 1) * 32, wn0 = (wave & 1) * 64;
    int bm = blockIdx.x * 64, bn = blockIdx.y * 128;

    int arow = tid >> 2, acol = (tid & 3) * 16;   // A: 64 rows x 64 k
    int agrow = bm + arow;
    int brow = tid >> 1, bkk = (tid & 1) * 32;    // B: 128 rows x 64 k

    f32x4 acc[2][4] = {};
    float4 a32[2][4];
    bf16x8 a16[2][2];
    bf16x8 breg[2][4];

    auto issue = [&](int it, int s) {
        int k0 = it * 64;
        if (A_IS_BF16) {
            a16[s][0] = bf16x8{};
            a16[s][1] = bf16x8{};
            if (agrow < M) {
                const ushort* ap = (const ushort*)Av + (size_t)agrow * KT + k0 + acol;
                a16[s][0] = *(const bf16x8*)ap;
                a16[s][1] = *(const bf16x8*)(ap + 8);
            }
        } else {
            a32[s][0] = a32[s][1] = a32[s][2] = a32[s][3] = make_float4(0.f, 0.f, 0.f, 0.f);
            if (agrow < M) {
                const float* ap = (const float*)Av + (size_t)agrow * KT + k0 + acol;
                a32[s][0] = *(const float4*)ap;
                a32[s][1] = *(const float4*)(ap + 4);
                a32[s][2] = *(const float4*)(ap + 8);
                a32[s][3] = *(const float4*)(ap + 12);
            }
        }
        const ushort* bp = Bt + (size_t)(bn + brow) * KT + k0 + bkk;
        breg[s][0] = *(const bf16x8*)bp;
        breg[s][1] = *(const bf16x8*)(bp + 8);
        breg[s][2] = *(const bf16x8*)(bp + 16);
        breg[s][3] = *(const bf16x8*)(bp + 24);
    };

    auto stage = [&](int s) {
        if (A_IS_BF16) {
            *(bf16x8*)&As[arow * LDK + acol]     = a16[s][0];
            *(bf16x8*)&As[arow * LDK + acol + 8] = a16[s][1];
        } else {
            ushort t0[8] = {f2bf(a32[s][0].x), f2bf(a32[s][0].y), f2bf(a32[s][0].z), f2bf(a32[s][0].w),
                            f2bf(a32[s][1].x), f2bf(a32[s][1].y), f2bf(a32[s][1].z), f2bf(a32[s][1].w)};
            ushort t1[8] = {f2bf(a32[s][2].x), f2bf(a32[s][2].y), f2bf(a32[s][2].z), f2bf(a32[s][2].w),
                            f2bf(a32[s][3].x), f2bf(a32[s][3].y), f2bf(a32[s][3].z), f2bf(a32[s][3].w)};
            *(bf16x8*)&As[arow * LDK + acol]     = *(bf16x8*)t0;
            *(bf16x8*)&As[arow * LDK + acol + 8] = *(bf16x8*)t1;
        }
        *(bf16x8*)&Bs[brow * LDK + bkk]      = breg[s][0];
        *(bf16x8*)&Bs[brow * LDK + bkk + 8]  = breg[s][1];
        *(bf16x8*)&Bs[brow * LDK + bkk + 16] = breg[s][2];
        *(bf16x8*)&Bs[brow * LDK + bkk + 24] = breg[s][3];
    };

    issue(0, 0);
    #pragma unroll
    for (int it = 0; it < NIT; ++it) {
        int cur = it & 1;
        if (it + 1 < NIT) issue(it + 1, cur ^ 1);
        if (it > 0) __syncthreads();
        stage(cur);
        __syncthreads();
        bf16x8 af[2][2], bfr[4][2];
        #pragma unroll
        for (int im = 0; im < 2; ++im)
            #pragma unroll
            for (int kh = 0; kh < 2; ++kh)
                af[im][kh] = *(bf16x8*)&As[(wm0 + im * 16 + l16) * LDK + kh * 32 + quad * 8];
        #pragma unroll
        for (int in = 0; in < 4; ++in)
            #pragma unroll
            for (int kh = 0; kh < 2; ++kh)
                bfr[in][kh] = *(bf16x8*)&Bs[(wn0 + in * 16 + l16) * LDK + kh * 32 + quad * 8];
        #pragma unroll
        for (int im = 0; im < 2; ++im)
            #pragma unroll
            for (int in = 0; in < 4; ++in) {
                acc[im][in] = __builtin_amdgcn_mfma_f32_16x16x32_bf16(
                    af[im][0], bfr[in][0], acc[im][in], 0, 0, 0);
                acc[im][in] = __builtin_amdgcn_mfma_f32_16x16x32_bf16(
                    af[im][1], bfr[in][1], acc[im][in], 0, 0, 0);
            }
    }
    #pragma unroll
    for (int im = 0; im < 2; ++im) {
        #pragma unroll
        for (int in = 0; in < 4; ++in) {
            int col = bn + wn0 + in * 16 + l16;
            float bval = bias ? bias[col] : 0.f;
            #pragma unroll
            for (int r = 0; r < 4; ++r) {
                int grow = bm + wm0 + im * 16 + quad * 4 + r;
                if (grow < M) {
                    float o = acc[im][in][r] + bval;
                    if (BF16OUT)
                        ((ushort*)Cv)[(size_t)grow * N + col] = f2bf(o);
                    else
                        ((float*)Cv)[(size_t)grow * N + col] = o;
                }
            }
        }
    }
}

// ---------------- gather ----------------
// convb[d][:] = bf16( di*( sum_in w_s*h[s][:] + di*h[d][:] ) + b_conv )
// wave64 per node; two 32-lane halves process alternate edges; unroll 8 per half
// (16 h-row loads in flight per wave). launch_bounds(256,4): 5 waves/SIMD.
__device__ __forceinline__ void acc_edge(float4& acc, unsigned r,
                                         const ushort* __restrict__ hb, int c) {
    unsigned s = r & 0xffffu;
    float w = __half2float(__ushort_as_half((ushort)(r >> 16)));
    uint2 v = *(const uint2*)&hb[(size_t)s * HID + c];
    acc.x += w * __uint_as_float(v.x << 16);
    acc.y += w * __uint_as_float(v.x & 0xffff0000u);
    acc.z += w * __uint_as_float(v.y << 16);
    acc.w += w * __uint_as_float(v.y & 0xffff0000u);
}

__global__ __launch_bounds__(256, 4) void gather_kernel(
    const ushort* __restrict__ hb, const int* __restrict__ row_ptr,
    const unsigned* __restrict__ rec, const float* __restrict__ dinv,
    const float* __restrict__ b_conv, ushort* __restrict__ convb, int n)
{
    int wave = threadIdx.x >> 6;
    int lane = threadIdx.x & 63;
    int d = blockIdx.x * 4 + wave;
    if (d >= n) return;
    int half = lane >> 5;
    int l32 = lane & 31;
    int c = l32 << 2;                 // 4 cols per lane

    float4 acc = make_float4(0.f, 0.f, 0.f, 0.f);
    int begin = row_ptr[d], end = row_ptr[d + 1];
    int e = begin + half;             // this half's edges: e, e+2, e+4, ...
    for (; e + 14 < end; e += 16) {   // 8 edges per half per iter
        unsigned r0 = rec[e];
        unsigned r1 = rec[e + 2];
        unsigned r2 = rec[e + 4];
        unsigned r3 = rec[e + 6];
        unsigned r4 = rec[e + 8];
        unsigned r5 = rec[e + 10];
        unsigned r6 = rec[e + 12];
        unsigned r7 = rec[e + 14];
        acc_edge(acc, r0, hb, c);
        acc_edge(acc, r1, hb, c);
        acc_edge(acc, r2, hb, c);
        acc_edge(acc, r3, hb, c);
        acc_edge(acc, r4, hb, c);
        acc_edge(acc, r5, hb, c);
        acc_edge(acc, r6, hb, c);
        acc_edge(acc, r7, hb, c);
    }
    for (; e + 6 < end; e += 8) {
        unsigned r0 = rec[e];
        unsigned r1 = rec[e + 2];
        unsigned r2 = rec[e + 4];
        unsigned r3 = rec[e + 6];
        acc_edge(acc, r0, hb, c);
        acc_edge(acc, r1, hb, c);
        acc_edge(acc, r2, hb, c);
        acc_edge(acc, r3, hb, c);
    }
    for (; e < end; e += 2) {
        unsigned r0 = rec[e];
        acc_edge(acc, r0, hb, c);
    }
    acc.x += __shfl_xor(acc.x, 32);
    acc.y += __shfl_xor(acc.y, 32);
    acc.z += __shfl_xor(acc.z, 32);
    acc.w += __shfl_xor(acc.w, 32);

    if (half == 0) {
        float di = dinv[d];
        uint2 hv = *(const uint2*)&hb[(size_t)d * HID + c];
        acc.x += di * __uint_as_float(hv.x << 16);
        acc.y += di * __uint_as_float(hv.x & 0xffff0000u);
        acc.z += di * __uint_as_float(hv.y << 16);
        acc.w += di * __uint_as_float(hv.y & 0xffff0000u);
        float4 bb = *(const float4*)&b_conv[c];
        float ox = di * acc.x + bb.x;
        float oy = di * acc.y + bb.y;
        float oz = di * acc.z + bb.z;
        float ow = di * acc.w + bb.w;
        uint2 po;
        po.x = ((unsigned)f2bf(oy) << 16) | (unsigned)f2bf(ox);
        po.y = ((unsigned)f2bf(ow) << 16) | (unsigned)f2bf(oz);
        *(uint2*)&convb[(size_t)d * HID + c] = po;
    }
}

extern "C" void kernel_launch(void* const* d_in, const int* in_sizes, int n_in,
                              void* d_out, int out_size, void* d_ws, size_t ws_size,
                              hipStream_t stream) {
    const float* x      = (const float*)d_in[0];
    const int*   ei     = (const int*)d_in[1];
    const float* W_conv = (const float*)d_in[2];
    const float* b_conv = (const float*)d_in[3];
    const float* W_lin  = (const float*)d_in[4];
    const float* b_lin  = (const float*)d_in[5];
    float* out = (float*)d_out;

    char* ws = (char*)d_ws;
    ushort* hb      = (ushort*)(ws + OFF_H);
    ushort* convb   = (ushort*)(ws + OFF_CONV);
    int*    deg     = (int*)(ws + OFF_DEG);
    int*    row_ptr = (int*)(ws + OFF_RP);
    float*  dinv    = (float*)(ws + OFF_DINV);
    ushort* rank    = (ushort*)(ws + OFF_RANK);
    unsigned* rec   = (unsigned*)(ws + OFF_REC);
    ushort* wt_conv = (ushort*)(ws + OFF_WT1);
    ushort* wt_lin  = (ushort*)(ws + OFF_WT2);

    const int* src = ei;
    const int* dst = ei + N_EDGES;

    hipMemsetAsync(deg, 0, 200000, stream);

    // K1: W transposes + deg/rank
    prep_kernel<<<PREP_BLOCKS, 256, 0, stream>>>(W_conv, W_lin, wt_conv, wt_lin,
                                                 dst, rank, deg);

    // K2: merged scan + finalize (row_ptr + dinv)
    scanfin_kernel<<<SCAN_BLOCKS, 256, 0, stream>>>(deg, row_ptr, dinv, N_NODES);

    // K3: CSR fill
    bucket_kernel<<<BUCKET_BLOCKS, 256, 0, stream>>>(src, dst, rank, row_ptr, dinv, rec);

    // K4: h = bf16(x @ W_conv) — register-prefetch GEMM
    mfma_gemm_kernel<IN_C, false, true><<<dim3(GEMM_MBLK, HID / 128), 256, 0, stream>>>(
        x, wt_conv, nullptr, hb, N_NODES, HID);

    // K5: gather (MLP x2)
    gather_kernel<<<(N_NODES + 3) / 4, 256, 0, stream>>>(
        hb, row_ptr, rec, dinv, b_conv, convb, N_NODES);

    // K6: out = conv @ W_lin + b_lin — register-prefetch GEMM
    mfma_gemm_kernel<HID, true, false><<<dim3(GEMM_MBLK, IN_C / 128), 256, 0, stream>>>(
        convb, wt_lin, b_lin, out, N_NODES, IN_C);
}

// Round 10
// 230.751 us; speedup vs baseline: 1.1593x; 1.0235x over previous
//
#include <hip/hip_runtime.h>
#include <hip/hip_fp16.h>

// GCN layer: h = x @ W_conv; conv = D^-1/2 (A+I) D^-1/2 h + b_conv; out = conv @ W_lin + b_lin
// N=50000, E=800000, in_c=256, hid=128.
// h, conv in bf16 row-major. CSR stored as packed u32 records (src u16 | fp16 weight).
//
// FINAL (R10): revert to the measured-best R7 configuration (229.0us).
// Session findings baked into this structure:
//  - BK=64 reg-prefetch GEMMs (issue iter k+1's loads before iter k's barriers).
//  - gather: wave/node, 2x32-lane halves, 8-edge unroll (16 row-loads in flight).
//  - NO software grid barriers (R5: agent-scope spin = 477us on non-coherent XCDs).
//  - NO block-range fusion of latency-bound + LDS-heavy roles (R3/R6: occupancy tax).
//  - NO redundant-recompute merges unless work << ~10us/dispatch gap (R8: 64us).
// Remaining ~80us is stream-serialization/launch floor; not kernel-counter-visible.
//
// Pipeline (8 dispatches, stream-serial):
//   memset(deg) -> prep(W transposes + deg/rank) -> scan_blocks -> finalize2
//   -> bucket -> GEMM1 (reg-prefetch) -> gather (MLP x2) -> GEMM2 (reg-prefetch)

#define N_NODES 50000
#define N_EDGES 800000
#define IN_C 256
#define HID 128
#define SCAN_BLOCKS ((N_NODES + 255) / 256)   // 196
#define GEMM_MBLK ((N_NODES + 63) / 64)       // 782
#define PREP_BLOCKS 1024
#define BUCKET_BLOCKS 2048                    // 8 classes x 256 chunk-blocks, 0 LDS
#define LDK 72                                 // 64 + 8 pad (bf16 elems)

// workspace layout (bytes)
#define OFF_H    0UL          // [N][128] bf16 = 12,800,000
#define OFF_CONV 12800000UL   // [N][128] bf16 = 12,800,000
#define OFF_DEG  25600000UL   // 50000 i32
#define OFF_RP   25800000UL   // 50001 i32 (pad to 64)
#define OFF_DINV 26000064UL   // 50000 f32
#define OFF_RANK 26200064UL   // 800000 u16 = 1,600,000
#define OFF_REC  27800064UL   // 800000 u32 = 3,200,000
#define OFF_BSUM 31000064UL   // 256 i32
#define OFF_WT1  31001088UL   // 128*256 bf16 (W_conv^T)
#define OFF_WT2  31066624UL   // 256*128 bf16 (W_lin^T)

typedef __attribute__((ext_vector_type(8))) short bf16x8;
typedef __attribute__((ext_vector_type(4))) float f32x4;

__device__ __forceinline__ ushort f2bf(float x) {
    unsigned u = __float_as_uint(x);
    u += 0x7fffu + ((u >> 16) & 1u);       // round-to-nearest-even
    return (ushort)(u >> 16);
}

// fused: transpose both weight matrices to bf16 [N][K] + deg count / rank capture.
// deg must be zeroed before this kernel (memset on the same stream).
__global__ __launch_bounds__(256) void prep_kernel(
    const float* __restrict__ Wc, const float* __restrict__ Wl,
    ushort* __restrict__ wtc, ushort* __restrict__ wtl,
    const int* __restrict__ dst, ushort* __restrict__ rank, int* __restrict__ deg)
{
    int i = blockIdx.x * 256 + threadIdx.x;
    if (i < HID * IN_C) {                            // W_conv [256][128] -> [128][256]
        int n = i / IN_C, k = i % IN_C;
        wtc[i] = f2bf(Wc[k * HID + n]);
    } else if (i < 2 * HID * IN_C) {                 // W_lin [128][256] -> [256][128]
        int j = i - HID * IN_C;
        int n = j / HID, k = j % HID;
        wtl[j] = f2bf(Wl[k * IN_C + n]);
    }
    for (int e = i; e < N_EDGES; e += PREP_BLOCKS * 256)
        rank[e] = (ushort)atomicAdd(&deg[dst[e]], 1);
}

__global__ __launch_bounds__(256) void scan_blocks_kernel(
    const int* __restrict__ deg, int* __restrict__ row_ptr,
    int* __restrict__ bsums, int n)
{
    __shared__ int tmp[256];
    int tid = threadIdx.x;
    int i = blockIdx.x * 256 + tid;
    int v = (i < n) ? deg[i] : 0;
    int orig = v;
    tmp[tid] = v;
    __syncthreads();
    #pragma unroll
    for (int off = 1; off < 256; off <<= 1) {
        int t = (tid >= off) ? tmp[tid - off] : 0;
        __syncthreads();
        tmp[tid] += t;
        __syncthreads();
    }
    if (i < n) row_ptr[i] = tmp[tid] - orig;
    if (tid == 255) bsums[blockIdx.x] = tmp[255];
}

// finalize with inlined block-sum scan: every block redundantly scans bsums[0..195]
// in LDS, then applies its own exclusive offset.
__global__ __launch_bounds__(256) void finalize2_kernel(
    const int* __restrict__ deg, int* __restrict__ row_ptr,
    const int* __restrict__ bsums, float* __restrict__ dinv, int n)
{
    __shared__ int tmp[256];
    __shared__ int orig[256];
    int tid = threadIdx.x;
    int v = (tid < SCAN_BLOCKS) ? bsums[tid] : 0;
    tmp[tid] = v;
    orig[tid] = v;
    __syncthreads();
    #pragma unroll
    for (int off = 1; off < 256; off <<= 1) {
        int t = (tid >= off) ? tmp[tid - off] : 0;
        __syncthreads();
        tmp[tid] += t;
        __syncthreads();
    }
    int boff = tmp[blockIdx.x] - orig[blockIdx.x];   // exclusive prefix for this block
    int i = blockIdx.x * 256 + tid;
    if (i < n) {
        row_ptr[i] += boff;
        dinv[i] = rsqrtf((float)(deg[i] + 1));
    }
    if (i == 0) row_ptr[n] = N_EDGES;
}

// CSR fill, atomic-free, XCD-class filtered (blockIdx%8 handles one dst range), 0 LDS.
__global__ __launch_bounds__(256) void bucket_kernel(
    const int* __restrict__ src, const int* __restrict__ dst,
    const ushort* __restrict__ rank, const int* __restrict__ row_ptr,
    const float* __restrict__ dinv, unsigned* __restrict__ rec)
{
    int cls = blockIdx.x & 7;
    int blk = blockIdx.x >> 3;                 // 0..255
    int lo = cls * (N_NODES / 8);              // 6250 per class
    int hi = lo + (N_NODES / 8);
    const int CHUNK = (N_EDGES + 255) / 256;   // 3125
    int e0 = blk * CHUNK;
    int e1 = min(e0 + CHUNK, N_EDGES);
    for (int i = e0 + threadIdx.x; i < e1; i += 256) {
        int d = dst[i];
        if (d >= lo && d < hi) {
            int s = src[i];
            unsigned r = (unsigned)(ushort)s |
                         ((unsigned)__half_as_ushort(__float2half_rn(dinv[s])) << 16);
            rec[row_ptr[d] + rank[i]] = r;
        }
    }
}

// ---------------- register-prefetch MFMA GEMM ----------------
// C[M,N] = A[M,KT] @ B[KT,N] (+bias). Tile 64x128, BK=64, KT compile-time.
// Iter k+1's global loads are issued BEFORE iter k's barriers/MFMA.
template <int KT, bool A_IS_BF16, bool BF16OUT>
__global__ __launch_bounds__(256) void mfma_gemm_kernel(
    const void* __restrict__ Av, const ushort* __restrict__ Bt,
    const float* __restrict__ bias, void* __restrict__ Cv,
    int M, int N)
{
    constexpr int NIT = KT / 64;
    __shared__ __align__(16) ushort As[64 * LDK];
    __shared__ __align__(16) ushort Bs[128 * LDK];
    int tid = threadIdx.x;
    int wave = tid >> 6, lane = tid & 63;
    int quad = lane >> 4, l16 = lane & 15;
    int wm0 = (wave >> 1) * 32, wn0 = (wave & 1) * 64;
    int bm = blockIdx.x * 64, bn = blockIdx.y * 128;

    int arow = tid >> 2, acol = (tid & 3) * 16;   // A: 64 rows x 64 k
    int agrow = bm + arow;
    int brow = tid >> 1, bkk = (tid & 1) * 32;    // B: 128 rows x 64 k

    f32x4 acc[2][4] = {};
    float4 a32[2][4];
    bf16x8 a16[2][2];
    bf16x8 breg[2][4];

    auto issue = [&](int it, int s) {
        int k0 = it * 64;
        if (A_IS_BF16) {
            a16[s][0] = bf16x8{};
            a16[s][1] = bf16x8{};
            if (agrow < M) {
                const ushort* ap = (const ushort*)Av + (size_t)agrow * KT + k0 + acol;
                a16[s][0] = *(const bf16x8*)ap;
                a16[s][1] = *(const bf16x8*)(ap + 8);
            }
        } else {
            a32[s][0] = a32[s][1] = a32[s][2] = a32[s][3] = make_float4(0.f, 0.f, 0.f, 0.f);
            if (agrow < M) {
                const float* ap = (const float*)Av + (size_t)agrow * KT + k0 + acol;
                a32[s][0] = *(const float4*)ap;
                a32[s][1] = *(const float4*)(ap + 4);
                a32[s][2] = *(const float4*)(ap + 8);
                a32[s][3] = *(const float4*)(ap + 12);
            }
        }
        const ushort* bp = Bt + (size_t)(bn + brow) * KT + k0 + bkk;
        breg[s][0] = *(const bf16x8*)bp;
        breg[s][1] = *(const bf16x8*)(bp + 8);
        breg[s][2] = *(const bf16x8*)(bp + 16);
        breg[s][3] = *(const bf16x8*)(bp + 24);
    };

    auto stage = [&](int s) {
        if (A_IS_BF16) {
            *(bf16x8*)&As[arow * LDK + acol]     = a16[s][0];
            *(bf16x8*)&As[arow * LDK + acol + 8] = a16[s][1];
        } else {
            ushort t0[8] = {f2bf(a32[s][0].x), f2bf(a32[s][0].y), f2bf(a32[s][0].z), f2bf(a32[s][0].w),
                            f2bf(a32[s][1].x), f2bf(a32[s][1].y), f2bf(a32[s][1].z), f2bf(a32[s][1].w)};
            ushort t1[8] = {f2bf(a32[s][2].x), f2bf(a32[s][2].y), f2bf(a32[s][2].z), f2bf(a32[s][2].w),
                            f2bf(a32[s][3].x), f2bf(a32[s][3].y), f2bf(a32[s][3].z), f2bf(a32[s][3].w)};
            *(bf16x8*)&As[arow * LDK + acol]     = *(bf16x8*)t0;
            *(bf16x8*)&As[arow * LDK + acol + 8] = *(bf16x8*)t1;
        }
        *(bf16x8*)&Bs[brow * LDK + bkk]      = breg[s][0];
        *(bf16x8*)&Bs[brow * LDK + bkk + 8]  = breg[s][1];
        *(bf16x8*)&Bs[brow * LDK + bkk + 16] = breg[s][2];
        *(bf16x8*)&Bs[brow * LDK + bkk + 24] = breg[s][3];
    };

    issue(0, 0);
    #pragma unroll
    for (int it = 0; it < NIT; ++it) {
        int cur = it & 1;
        if (it + 1 < NIT) issue(it + 1, cur ^ 1);
        if (it > 0) __syncthreads();
        stage(cur);
        __syncthreads();
        bf16x8 af[2][2], bfr[4][2];
        #pragma unroll
        for (int im = 0; im < 2; ++im)
            #pragma unroll
            for (int kh = 0; kh < 2; ++kh)
                af[im][kh] = *(bf16x8*)&As[(wm0 + im * 16 + l16) * LDK + kh * 32 + quad * 8];
        #pragma unroll
        for (int in = 0; in < 4; ++in)
            #pragma unroll
            for (int kh = 0; kh < 2; ++kh)
                bfr[in][kh] = *(bf16x8*)&Bs[(wn0 + in * 16 + l16) * LDK + kh * 32 + quad * 8];
        #pragma unroll
        for (int im = 0; im < 2; ++im)
            #pragma unroll
            for (int in = 0; in < 4; ++in) {
                acc[im][in] = __builtin_amdgcn_mfma_f32_16x16x32_bf16(
                    af[im][0], bfr[in][0], acc[im][in], 0, 0, 0);
                acc[im][in] = __builtin_amdgcn_mfma_f32_16x16x32_bf16(
                    af[im][1], bfr[in][1], acc[im][in], 0, 0, 0);
            }
    }
    #pragma unroll
    for (int im = 0; im < 2; ++im) {
        #pragma unroll
        for (int in = 0; in < 4; ++in) {
            int col = bn + wn0 + in * 16 + l16;
            float bval = bias ? bias[col] : 0.f;
            #pragma unroll
            for (int r = 0; r < 4; ++r) {
                int grow = bm + wm0 + im * 16 + quad * 4 + r;
                if (grow < M) {
                    float o = acc[im][in][r] + bval;
                    if (BF16OUT)
                        ((ushort*)Cv)[(size_t)grow * N + col] = f2bf(o);
                    else
                        ((float*)Cv)[(size_t)grow * N + col] = o;
                }
            }
        }
    }
}

// ---------------- gather ----------------
// convb[d][:] = bf16( di*( sum_in w_s*h[s][:] + di*h[d][:] ) + b_conv )
// wave64 per node; two 32-lane halves process alternate edges; unroll 8 per half
// (16 h-row loads in flight per wave). launch_bounds(256,4): 5 waves/SIMD.
__device__ __forceinline__ void acc_edge(float4& acc, unsigned r,
                                         const ushort* __restrict__ hb, int c) {
    unsigned s = r & 0xffffu;
    float w = __half2float(__ushort_as_half((ushort)(r >> 16)));
    uint2 v = *(const uint2*)&hb[(size_t)s * HID + c];
    acc.x += w * __uint_as_float(v.x << 16);
    acc.y += w * __uint_as_float(v.x & 0xffff0000u);
    acc.z += w * __uint_as_float(v.y << 16);
    acc.w += w * __uint_as_float(v.y & 0xffff0000u);
}

__global__ __launch_bounds__(256, 4) void gather_kernel(
    const ushort* __restrict__ hb, const int* __restrict__ row_ptr,
    const unsigned* __restrict__ rec, const float* __restrict__ dinv,
    const float* __restrict__ b_conv, ushort* __restrict__ convb, int n)
{
    int wave = threadIdx.x >> 6;
    int lane = threadIdx.x & 63;
    int d = blockIdx.x * 4 + wave;
    if (d >= n) return;
    int half = lane >> 5;
    int l32 = lane & 31;
    int c = l32 << 2;                 // 4 cols per lane

    float4 acc = make_float4(0.f, 0.f, 0.f, 0.f);
    int begin = row_ptr[d], end = row_ptr[d + 1];
    int e = begin + half;             // this half's edges: e, e+2, e+4, ...
    for (; e + 14 < end; e += 16) {   // 8 edges per half per iter
        unsigned r0 = rec[e];
        unsigned r1 = rec[e + 2];
        unsigned r2 = rec[e + 4];
        unsigned r3 = rec[e + 6];
        unsigned r4 = rec[e + 8];
        unsigned r5 = rec[e + 10];
        unsigned r6 = rec[e + 12];
        unsigned r7 = rec[e + 14];
        acc_edge(acc, r0, hb, c);
        acc_edge(acc, r1, hb, c);
        acc_edge(acc, r2, hb, c);
        acc_edge(acc, r3, hb, c);
        acc_edge(acc, r4, hb, c);
        acc_edge(acc, r5, hb, c);
        acc_edge(acc, r6, hb, c);
        acc_edge(acc, r7, hb, c);
    }
    for (; e + 6 < end; e += 8) {
        unsigned r0 = rec[e];
        unsigned r1 = rec[e + 2];
        unsigned r2 = rec[e + 4];
        unsigned r3 = rec[e + 6];
        acc_edge(acc, r0, hb, c);
        acc_edge(acc, r1, hb, c);
        acc_edge(acc, r2, hb, c);
        acc_edge(acc, r3, hb, c);
    }
    for (; e < end; e += 2) {
        unsigned r0 = rec[e];
        acc_edge(acc, r0, hb, c);
    }
    acc.x += __shfl_xor(acc.x, 32);
    acc.y += __shfl_xor(acc.y, 32);
    acc.z += __shfl_xor(acc.z, 32);
    acc.w += __shfl_xor(acc.w, 32);

    if (half == 0) {
        float di = dinv[d];
        uint2 hv = *(const uint2*)&hb[(size_t)d * HID + c];
        acc.x += di * __uint_as_float(hv.x << 16);
        acc.y += di * __uint_as_float(hv.x & 0xffff0000u);
        acc.z += di * __uint_as_float(hv.y << 16);
        acc.w += di * __uint_as_float(hv.y & 0xffff0000u);
        float4 bb = *(const float4*)&b_conv[c];
        float ox = di * acc.x + bb.x;
        float oy = di * acc.y + bb.y;
        float oz = di * acc.z + bb.z;
        float ow = di * acc.w + bb.w;
        uint2 po;
        po.x = ((unsigned)f2bf(oy) << 16) | (unsigned)f2bf(ox);
        po.y = ((unsigned)f2bf(ow) << 16) | (unsigned)f2bf(oz);
        *(uint2*)&convb[(size_t)d * HID + c] = po;
    }
}

extern "C" void kernel_launch(void* const* d_in, const int* in_sizes, int n_in,
                              void* d_out, int out_size, void* d_ws, size_t ws_size,
                              hipStream_t stream) {
    const float* x      = (const float*)d_in[0];
    const int*   ei     = (const int*)d_in[1];
    const float* W_conv = (const float*)d_in[2];
    const float* b_conv = (const float*)d_in[3];
    const float* W_lin  = (const float*)d_in[4];
    const float* b_lin  = (const float*)d_in[5];
    float* out = (float*)d_out;

    char* ws = (char*)d_ws;
    ushort* hb      = (ushort*)(ws + OFF_H);
    ushort* convb   = (ushort*)(ws + OFF_CONV);
    int*    deg     = (int*)(ws + OFF_DEG);
    int*    row_ptr = (int*)(ws + OFF_RP);
    float*  dinv    = (float*)(ws + OFF_DINV);
    ushort* rank    = (ushort*)(ws + OFF_RANK);
    unsigned* rec   = (unsigned*)(ws + OFF_REC);
    int*    bsums   = (int*)(ws + OFF_BSUM);
    ushort* wt_conv = (ushort*)(ws + OFF_WT1);
    ushort* wt_lin  = (ushort*)(ws + OFF_WT2);

    const int* src = ei;
    const int* dst = ei + N_EDGES;

    hipMemsetAsync(deg, 0, 200000, stream);

    // K1: W transposes + deg/rank
    prep_kernel<<<PREP_BLOCKS, 256, 0, stream>>>(W_conv, W_lin, wt_conv, wt_lin,
                                                 dst, rank, deg);
    // K2-K3: CSR scan
    scan_blocks_kernel<<<SCAN_BLOCKS, 256, 0, stream>>>(deg, row_ptr, bsums, N_NODES);
    finalize2_kernel<<<SCAN_BLOCKS, 256, 0, stream>>>(deg, row_ptr, bsums, dinv, N_NODES);

    // K4: CSR fill
    bucket_kernel<<<BUCKET_BLOCKS, 256, 0, stream>>>(src, dst, rank, row_ptr, dinv, rec);

    // K5: h = bf16(x @ W_conv) — register-prefetch GEMM
    mfma_gemm_kernel<IN_C, false, true><<<dim3(GEMM_MBLK, HID / 128), 256, 0, stream>>>(
        x, wt_conv, nullptr, hb, N_NODES, HID);

    // K6: gather (MLP x2)
    gather_kernel<<<(N_NODES + 3) / 4, 256, 0, stream>>>(
        hb, row_ptr, rec, dinv, b_conv, convb, N_NODES);

    // K7: out = conv @ W_lin + b_lin — register-prefetch GEMM
    mfma_gemm_kernel<HID, true, false><<<dim3(GEMM_MBLK, IN_C / 128), 256, 0, stream>>>(
        convb, wt_lin, b_lin, out, N_NODES, IN_C);
}